// Round 11
// baseline (1089.854 us; speedup 1.0000x reference)
//
#include <hip/hip_runtime.h>
#include <hip/hip_bf16.h>

#define S_    2048
#define D_    1024
#define H_    16
#define HD_   64
#define NB_   4

// DIAGNOSTIC BUILD: attn body repeated 3x (idempotent) to lift the attn
// dispatch above the harness fillBuffer dispatches (~670 us) so it appears
// in the rocprof top-5 with counters. attn_true = dur/3.
#define ATTN_REPS 3

using bf16x8 = __attribute__((ext_vector_type(8))) short;
using bf16x4 = __attribute__((ext_vector_type(4))) short;
using f32x4  = __attribute__((ext_vector_type(4))) float;

static __device__ __forceinline__ short f2bf(float f) {
  unsigned u = __builtin_bit_cast(unsigned, f);
  u += 0x7fffu + ((u >> 16) & 1u);        // RNE
  return (short)(u >> 16);
}
static __device__ __forceinline__ unsigned pk2(float a, float b) {
  return (unsigned)(unsigned short)f2bf(a) | ((unsigned)(unsigned short)f2bf(b) << 16);
}

// async global->LDS, 16B per lane. LDS dest is wave-uniform base + lane*16.
static __device__ __forceinline__ void gld16(const short* g, short* l) {
  __builtin_amdgcn_global_load_lds(
      (const __attribute__((address_space(1))) void*)g,
      (__attribute__((address_space(3))) void*)l, 16, 0, 0);
}

// ---------------- cast f32 -> bf16 (n multiple of 8) ----------------
__global__ __launch_bounds__(256) void cast_kernel(const float* __restrict__ src,
                                                   short* __restrict__ dst, int n8) {
  int i = blockIdx.x * 256 + threadIdx.x;
  if (i >= n8) return;
  f32x4 a = reinterpret_cast<const f32x4*>(src)[2 * i];
  f32x4 b = reinterpret_cast<const f32x4*>(src)[2 * i + 1];
  bf16x8 o;
  o[0] = f2bf(a[0]); o[1] = f2bf(a[1]); o[2] = f2bf(a[2]); o[3] = f2bf(a[3]);
  o[4] = f2bf(b[0]); o[5] = f2bf(b[1]); o[6] = f2bf(b[2]); o[7] = f2bf(b[3]);
  reinterpret_cast<bf16x8*>(dst)[i] = o;
}

// ---------------- pack mask int32 -> TRANSPOSED bitmask ----------------
__global__ __launch_bounds__(256) void pack_mask(const int* __restrict__ mask,
                                                 unsigned long long* __restrict__ mp) {
  int i = blockIdx.x * 256 + threadIdx.x;   // i = (b*S + q)*S + k
  unsigned long long bits = __ballot(mask[i] != 0);
  if ((threadIdx.x & 63) == 0) {
    int k = i & 2047;
    int q = (i >> 11) & 2047;
    int b = i >> 22;
    mp[((size_t)(b * 32 + (k >> 6))) * 2048 + q] = bits;
  }
}

// ---------------- Wt[n][k] = (bf16) W[k][n], 1024x1024 ----------------
__global__ __launch_bounds__(256) void transpose_cast_kernel(const float* __restrict__ W,
                                                             short* __restrict__ Wt) {
  __shared__ float tile[32][33];
  int tx = threadIdx.x, ty = threadIdx.y;           // (32, 8)
  int bx = blockIdx.x * 32, by = blockIdx.y * 32;
#pragma unroll
  for (int i = 0; i < 4; ++i) {
    int k = ty + 8 * i;
    tile[k][tx] = W[(size_t)(by + k) * D_ + bx + tx];
  }
  __syncthreads();
#pragma unroll
  for (int i = 0; i < 4; ++i) {
    int n = ty + 8 * i;
    Wt[(size_t)(bx + n) * D_ + by + tx] = f2bf(tile[tx][n]);
  }
}

// ---------------- GEMM: out = A[8192x1024] @ Bt^T + bias, m97-style ----------------
template <int MODE>
__global__ __launch_bounds__(256) void proj_gemm(const short* __restrict__ A,
                                                 const short* __restrict__ Bt,
                                                 const float* __restrict__ bias,
                                                 void* __restrict__ outp, float oscale) {
  __shared__ short As[128 * 64];
  __shared__ short Bs[128 * 64];
  const int t = threadIdx.x;
  const int w = t >> 6, l = t & 63, lr = l & 15, lg = l >> 4;
  const int rb = blockIdx.x, cb = blockIdx.y;
  const int wr = w >> 1, wc = w & 1;
  const f32x4 fz = {0.f, 0.f, 0.f, 0.f};
  f32x4 acc[4][4];
#pragma unroll
  for (int mi = 0; mi < 4; ++mi)
#pragma unroll
    for (int ni = 0; ni < 4; ++ni) acc[mi][ni] = fz;

  const int sr = l >> 3;
  const int sd = (l & 7) ^ sr;
  const short* Ag = A + ((size_t)(rb * 128 + w * 8 + sr)) * D_ + sd * 8;
  const short* Bg = Bt + ((size_t)(cb * 128 + w * 8 + sr)) * D_ + sd * 8;

  for (int k0 = 0; k0 < D_; k0 += 64) {
    __syncthreads();
#pragma unroll
    for (int i = 0; i < 4; ++i) {
      gld16(Ag + (size_t)(32 * i) * D_ + k0, &As[(4 * i + w) * 512]);
      gld16(Bg + (size_t)(32 * i) * D_ + k0, &Bs[(4 * i + w) * 512]);
    }
    __syncthreads();
#pragma unroll
    for (int kk = 0; kk < 2; ++kk) {
      bf16x8 af[4], bfr[4];
#pragma unroll
      for (int mi = 0; mi < 4; ++mi) {
        int r = wr * 64 + mi * 16 + lr;
        af[mi] = *reinterpret_cast<bf16x8*>(&As[r * 64 + (((4 * kk + lg) ^ (lr & 7)) * 8)]);
      }
#pragma unroll
      for (int ni = 0; ni < 4; ++ni) {
        int r = wc * 64 + ni * 16 + lr;
        bfr[ni] = *reinterpret_cast<bf16x8*>(&Bs[r * 64 + (((4 * kk + lg) ^ (lr & 7)) * 8)]);
      }
#pragma unroll
      for (int mi = 0; mi < 4; ++mi)
#pragma unroll
        for (int ni = 0; ni < 4; ++ni)
          acc[mi][ni] = __builtin_amdgcn_mfma_f32_16x16x32_bf16(af[mi], bfr[ni], acc[mi][ni], 0, 0, 0);
    }
  }

#pragma unroll
  for (int mi = 0; mi < 4; ++mi) {
#pragma unroll
    for (int ni = 0; ni < 4; ++ni) {
#pragma unroll
      for (int j = 0; j < 4; ++j) {
        int rr = rb * 128 + wr * 64 + mi * 16 + 4 * lg + j;
        int cc = cb * 128 + wc * 64 + ni * 16 + lr;
        float v = acc[mi][ni][j] + bias[cc];
        int b = rr >> 11, s = rr & 2047, h = cc >> 6, d = cc & 63;
        if (MODE == 0) {
          ((short*)outp)[(((size_t)(b * H_ + h)) * S_ + s) * HD_ + d] = f2bf(v * oscale);
        } else if (MODE == 1) {
          ((short*)outp)[(((size_t)(b * H_ + h)) * HD_ + d) * S_ + s] = f2bf(v);
        } else {
          ((float*)outp)[(size_t)rr * D_ + cc] = v;
        }
      }
    }
  }
}

// ---------------- fused attention (DIAGNOSTIC: body repeated ATTN_REPS times) ----------
__global__ __launch_bounds__(256, 2) void attn_kernel(const short* __restrict__ Q,
                                                      const short* __restrict__ K,
                                                      const short* __restrict__ Vt,
                                                      const unsigned long long* __restrict__ mT,
                                                      float* __restrict__ attn_out,
                                                      short* __restrict__ ctx) {
  __shared__ __attribute__((aligned(16))) char smem[26624];
  short* Ps  = (short*)smem;               // [4 waves][16][72] shorts (pass2 loop)
  float* mlb = (float*)(smem + 9216);      // [4][4][16] float (pass1 merge)
  float* c4  = (float*)smem;               // [4 waves][16 dcols][68] f32 (ctx merge)

  const int tid = threadIdx.x;
  const int w = tid >> 6, l = tid & 63, lr = l & 15, lg = l >> 4;
  const int bid = blockIdx.x;
  const int swz = (bid & 7) * 256 + (bid >> 3);  // bijective XCD swizzle (2048 = 8*256)
  const int qt = swz & 31, bh = swz >> 5;
  const int b = bh >> 4, h = bh & 15;

  const short* Qg = Q + ((size_t)bh * S_ + qt * 64) * HD_;
  const short* Kg = K + (size_t)bh * S_ * HD_;
  const short* Vg = Vt + (size_t)bh * HD_ * S_;
  const f32x4 fz = {0.f, 0.f, 0.f, 0.f};

  bf16x8 qf[4][2];
#pragma unroll
  for (int qa = 0; qa < 4; ++qa)
#pragma unroll
    for (int c = 0; c < 2; ++c)
      qf[qa][c] = *reinterpret_cast<const bf16x8*>(&Qg[(size_t)(16 * qa + lr) * HD_ + 32 * c + 8 * lg]);

#pragma unroll 1
  for (int rep = 0; rep < ATTN_REPS; ++rep) {
  __syncthreads();   // isolate reps: mlb/c4 alias across rep boundary

  float ls[4] = {0.f, 0.f, 0.f, 0.f};

  // ---------- pass 1: striped sum of exp2 ----------
#pragma unroll 1
  for (int t8 = 0; t8 < 8; ++t8) {
    const int kt = t8 * 4 + w;
    const short* kb = Kg + (size_t)kt * 64 * HD_;
    bf16x8 kf[4][2];
#pragma unroll
    for (int nf = 0; nf < 4; ++nf)
#pragma unroll
      for (int c = 0; c < 2; ++c)
        kf[nf][c] = *reinterpret_cast<const bf16x8*>(&kb[(size_t)(16 * nf + lr) * HD_ + 32 * c + 8 * lg]);
    unsigned long long mw[4];
#pragma unroll
    for (int qa = 0; qa < 4; ++qa)
      mw[qa] = mT[(size_t)(b * 32 + kt) * S_ + qt * 64 + 16 * qa + lr];
    __builtin_amdgcn_sched_barrier(0);

#pragma unroll
    for (int qa = 0; qa < 4; ++qa) {
      f32x4 sc[4];
      __builtin_amdgcn_s_setprio(1);
#pragma unroll
      for (int nf = 0; nf < 4; ++nf) {
        f32x4 a = fz;
        a = __builtin_amdgcn_mfma_f32_16x16x32_bf16(kf[nf][0], qf[qa][0], a, 0, 0, 0);
        a = __builtin_amdgcn_mfma_f32_16x16x32_bf16(kf[nf][1], qf[qa][1], a, 0, 0, 0);
        sc[nf] = a;
      }
      __builtin_amdgcn_s_setprio(0);
      float acc = 0.0f;
#pragma unroll
      for (int nf = 0; nf < 4; ++nf) {
        unsigned nib = (unsigned)(mw[qa] >> (16 * nf + 4 * lg)) & 0xFu;
        float e[4];
#pragma unroll
        for (int j = 0; j < 4; ++j) {
          float v = __builtin_amdgcn_exp2f(sc[nf][j]);
          e[j] = ((nib >> j) & 1) ? 0.0f : v;
        }
        acc += (e[0] + e[1]) + (e[2] + e[3]);
      }
      ls[qa] += acc;
    }
  }
#pragma unroll
  for (int off = 16; off < 64; off <<= 1)
#pragma unroll
    for (int qa = 0; qa < 4; ++qa) ls[qa] += __shfl_xor(ls[qa], off, 64);
  if (lg == 0) {
#pragma unroll
    for (int qa = 0; qa < 4; ++qa) mlb[(w * 4 + qa) * 16 + lr] = ls[qa];
  }
  __syncthreads();
  float rl[4];
#pragma unroll
  for (int qa = 0; qa < 4; ++qa) {
    float lt = (mlb[(0 * 4 + qa) * 16 + lr] + mlb[(1 * 4 + qa) * 16 + lr]) +
               (mlb[(2 * 4 + qa) * 16 + lr] + mlb[(3 * 4 + qa) * 16 + lr]);
    rl[qa] = 1.0f / lt;
  }

  // ---------- pass 2: write normalized attn + accumulate striped ctx ----------
  f32x4 ctxa[4][4];
#pragma unroll
  for (int qa = 0; qa < 4; ++qa)
#pragma unroll
    for (int df = 0; df < 4; ++df) ctxa[qa][df] = fz;
  short* Pw = Ps + w * 16 * 72;

#pragma unroll 1
  for (int t8 = 0; t8 < 8; ++t8) {
    const int kt = t8 * 4 + w;
    const short* kb = Kg + (size_t)kt * 64 * HD_;
    bf16x8 kf[4][2], vf[4][2];
#pragma unroll
    for (int nf = 0; nf < 4; ++nf)
#pragma unroll
      for (int c = 0; c < 2; ++c)
        kf[nf][c] = *reinterpret_cast<const bf16x8*>(&kb[(size_t)(16 * nf + lr) * HD_ + 32 * c + 8 * lg]);
#pragma unroll
    for (int df = 0; df < 4; ++df)
#pragma unroll
      for (int c = 0; c < 2; ++c)
        vf[df][c] = *reinterpret_cast<const bf16x8*>(&Vg[(size_t)(16 * df + lr) * S_ + kt * 64 + 32 * c + 8 * lg]);
    unsigned long long mw[4];
#pragma unroll
    for (int qa = 0; qa < 4; ++qa)
      mw[qa] = mT[(size_t)(b * 32 + kt) * S_ + qt * 64 + 16 * qa + lr];
    __builtin_amdgcn_sched_barrier(0);

#pragma unroll
    for (int qa = 0; qa < 4; ++qa) {
      f32x4 sc[4];
      __builtin_amdgcn_s_setprio(1);
#pragma unroll
      for (int nf = 0; nf < 4; ++nf) {
        f32x4 a = fz;
        a = __builtin_amdgcn_mfma_f32_16x16x32_bf16(kf[nf][0], qf[qa][0], a, 0, 0, 0);
        a = __builtin_amdgcn_mfma_f32_16x16x32_bf16(kf[nf][1], qf[qa][1], a, 0, 0, 0);
        sc[nf] = a;
      }
      __builtin_amdgcn_s_setprio(0);
      float* arow = attn_out + ((size_t)bh * S_ + (qt * 64 + 16 * qa + lr)) * S_ + kt * 64;
      uint2 U[4];
#pragma unroll
      for (int nf = 0; nf < 4; ++nf) {
        unsigned nib = (unsigned)(mw[qa] >> (16 * nf + 4 * lg)) & 0xFu;
        f32x4 pv;
#pragma unroll
        for (int j = 0; j < 4; ++j) {
          float e = __builtin_amdgcn_exp2f(sc[nf][j]) * rl[qa];
          pv[j] = ((nib >> j) & 1) ? 0.0f : e;
        }
        __builtin_nontemporal_store(pv, (f32x4*)(arow + 16 * nf + 4 * lg));
        U[nf].x = pk2(pv[0], pv[1]);
        U[nf].y = pk2(pv[2], pv[3]);
      }
#pragma unroll
      for (int nf = 0; nf < 4; ++nf)
        *reinterpret_cast<uint2*>(&Pw[lr * 72 + 16 * nf + 4 * lg]) = U[nf];
      __builtin_amdgcn_sched_barrier(0);
      asm volatile("s_waitcnt lgkmcnt(0)");
      __builtin_amdgcn_sched_barrier(0);
      bf16x8 pa0 = *reinterpret_cast<bf16x8*>(&Pw[lr * 72 + 8 * lg]);
      bf16x8 pa1 = *reinterpret_cast<bf16x8*>(&Pw[lr * 72 + 32 + 8 * lg]);
      __builtin_amdgcn_s_setprio(1);
#pragma unroll
      for (int df = 0; df < 4; ++df) {
        ctxa[qa][df] = __builtin_amdgcn_mfma_f32_16x16x32_bf16(pa0, vf[df][0], ctxa[qa][df], 0, 0, 0);
        ctxa[qa][df] = __builtin_amdgcn_mfma_f32_16x16x32_bf16(pa1, vf[df][1], ctxa[qa][df], 0, 0, 0);
      }
      __builtin_amdgcn_s_setprio(0);
    }
  }

  // ---------- cross-wave ctx reduction: 4 rounds of 16 d-columns ----------
  __syncthreads();
#pragma unroll
  for (int r = 0; r < 4; ++r) {
    if (r) __syncthreads();
#pragma unroll
    for (int qa = 0; qa < 4; ++qa)
      *reinterpret_cast<f32x4*>(&c4[(w * 16 + lr) * 68 + 16 * qa + 4 * lg]) = ctxa[qa][r];
    __syncthreads();
    int q = tid & 63, d0 = (tid >> 6) * 4;   // d0 in {0,4,8,12}
    float vs[4];
#pragma unroll
    for (int i = 0; i < 4; ++i) {
      int dl = d0 + i;
      vs[i] = (c4[(0 * 16 + dl) * 68 + q] + c4[(1 * 16 + dl) * 68 + q]) +
              (c4[(2 * 16 + dl) * 68 + q] + c4[(3 * 16 + dl) * 68 + q]);
    }
    bf16x4 o;
#pragma unroll
    for (int i = 0; i < 4; ++i) o[i] = f2bf(vs[i]);
    *reinterpret_cast<bf16x4*>(&ctx[((size_t)b * S_ + qt * 64 + q) * D_ + h * 64 + 16 * r + d0]) = o;
  }

  }  // rep
}

extern "C" void kernel_launch(void* const* d_in, const int* in_sizes, int n_in,
                              void* d_out, int out_size, void* d_ws, size_t ws_size,
                              hipStream_t stream) {
  const float* query = (const float*)d_in[0];
  const float* key   = (const float*)d_in[1];
  const float* value = (const float*)d_in[2];
  const int*   mask  = (const int*)d_in[3];
  const float* Wq = (const float*)d_in[4];
  const float* bq = (const float*)d_in[5];
  const float* Wk = (const float*)d_in[6];
  const float* bk = (const float*)d_in[7];
  const float* Wv = (const float*)d_in[8];
  const float* bv = (const float*)d_in[9];
  const float* Wo = (const float*)d_in[10];
  const float* bo = (const float*)d_in[11];

  char* ws = (char*)d_ws;
  const size_t BIG = 16777216;  // 8192*1024*2 bytes
  short* Xbuf  = (short*)(ws);
  short* Qbuf  = (short*)(ws + BIG);
  short* Kbuf  = (short*)(ws + 2 * BIG);
  short* Vtbuf = (short*)(ws + 3 * BIG);
  short* Wqt   = (short*)(ws + 4 * BIG);
  short* Wkt   = (short*)(ws + 4 * BIG + 2097152);
  short* Wvt   = (short*)(ws + 4 * BIG + 2 * 2097152);
  short* Wot   = (short*)(ws + 4 * BIG + 3 * 2097152);
  unsigned long long* maskp = (unsigned long long*)(ws + 4 * BIG + 4 * 2097152);  // 2 MB
  short* ctx   = Xbuf;  // reuse after projections

  float* out0 = (float*)d_out;
  float* attn_out = out0 + (size_t)NB_ * S_ * D_;  // 8388608

  // pack mask to transposed bit words
  pack_mask<<<(NB_ * S_ * S_) / 256, 256, 0, stream>>>(mask, maskp);

  dim3 tcb(32, 8), tcg(32, 32);
  transpose_cast_kernel<<<tcg, tcb, 0, stream>>>(Wq, Wqt);
  transpose_cast_kernel<<<tcg, tcb, 0, stream>>>(Wk, Wkt);
  transpose_cast_kernel<<<tcg, tcb, 0, stream>>>(Wv, Wvt);
  transpose_cast_kernel<<<tcg, tcb, 0, stream>>>(Wo, Wot);

  const int n8 = (NB_ * S_ * D_) / 8;  // 1048576
  dim3 gemm_g(64, 8);
  const float QSCALE = 0.125f * 1.4426950408889634f;  // SCALE * log2(e)

  cast_kernel<<<n8 / 256, 256, 0, stream>>>(query, Xbuf, n8);
  proj_gemm<0><<<gemm_g, 256, 0, stream>>>(Xbuf, Wqt, bq, Qbuf, QSCALE);
  cast_kernel<<<n8 / 256, 256, 0, stream>>>(key, Xbuf, n8);
  proj_gemm<0><<<gemm_g, 256, 0, stream>>>(Xbuf, Wkt, bk, Kbuf, 1.0f);
  cast_kernel<<<n8 / 256, 256, 0, stream>>>(value, Xbuf, n8);
  proj_gemm<1><<<gemm_g, 256, 0, stream>>>(Xbuf, Wvt, bv, Vtbuf, 1.0f);

  attn_kernel<<<2048, 256, 0, stream>>>(Qbuf, Kbuf, Vtbuf, maskp, attn_out, ctx);

  proj_gemm<2><<<gemm_g, 256, 0, stream>>>(ctx, Wot, bo, out0, 1.0f);
}

// Round 12
// 542.113 us; speedup vs baseline: 2.0104x; 2.0104x over previous
//
#include <hip/hip_runtime.h>
#include <hip/hip_bf16.h>

#define S_    2048
#define D_    1024
#define H_    16
#define HD_   64
#define NB_   4

using bf16x8 = __attribute__((ext_vector_type(8))) short;
using bf16x4 = __attribute__((ext_vector_type(4))) short;
using f32x4  = __attribute__((ext_vector_type(4))) float;

static __device__ __forceinline__ short f2bf(float f) {
  unsigned u = __builtin_bit_cast(unsigned, f);
  u += 0x7fffu + ((u >> 16) & 1u);        // RNE
  return (short)(u >> 16);
}
static __device__ __forceinline__ unsigned pk2(float a, float b) {
  return (unsigned)(unsigned short)f2bf(a) | ((unsigned)(unsigned short)f2bf(b) << 16);
}

// async global->LDS, 16B per lane. LDS dest is wave-uniform base + lane*16.
static __device__ __forceinline__ void gld16(const short* g, short* l) {
  __builtin_amdgcn_global_load_lds(
      (const __attribute__((address_space(1))) void*)g,
      (__attribute__((address_space(3))) void*)l, 16, 0, 0);
}

// ---------------- cast f32 -> bf16 (n multiple of 8) ----------------
__global__ __launch_bounds__(256) void cast_kernel(const float* __restrict__ src,
                                                   short* __restrict__ dst, int n8) {
  int i = blockIdx.x * 256 + threadIdx.x;
  if (i >= n8) return;
  f32x4 a = reinterpret_cast<const f32x4*>(src)[2 * i];
  f32x4 b = reinterpret_cast<const f32x4*>(src)[2 * i + 1];
  bf16x8 o;
  o[0] = f2bf(a[0]); o[1] = f2bf(a[1]); o[2] = f2bf(a[2]); o[3] = f2bf(a[3]);
  o[4] = f2bf(b[0]); o[5] = f2bf(b[1]); o[6] = f2bf(b[2]); o[7] = f2bf(b[3]);
  reinterpret_cast<bf16x8*>(dst)[i] = o;
}

// ---------------- pack mask int32 -> TRANSPOSED bitmask ----------------
__global__ __launch_bounds__(256) void pack_mask(const int* __restrict__ mask,
                                                 unsigned long long* __restrict__ mp) {
  int i = blockIdx.x * 256 + threadIdx.x;   // i = (b*S + q)*S + k
  unsigned long long bits = __ballot(mask[i] != 0);
  if ((threadIdx.x & 63) == 0) {
    int k = i & 2047;
    int q = (i >> 11) & 2047;
    int b = i >> 22;
    mp[((size_t)(b * 32 + (k >> 6))) * 2048 + q] = bits;
  }
}

// ---------------- Wt[n][k] = (bf16) W[k][n], 1024x1024 ----------------
__global__ __launch_bounds__(256) void transpose_cast_kernel(const float* __restrict__ W,
                                                             short* __restrict__ Wt) {
  __shared__ float tile[32][33];
  int tx = threadIdx.x, ty = threadIdx.y;           // (32, 8)
  int bx = blockIdx.x * 32, by = blockIdx.y * 32;
#pragma unroll
  for (int i = 0; i < 4; ++i) {
    int k = ty + 8 * i;
    tile[k][tx] = W[(size_t)(by + k) * D_ + bx + tx];
  }
  __syncthreads();
#pragma unroll
  for (int i = 0; i < 4; ++i) {
    int n = ty + 8 * i;
    Wt[(size_t)(bx + n) * D_ + by + tx] = f2bf(tile[tx][n]);
  }
}

// ---------------- GEMM: out = A[8192x1024] @ Bt^T + bias, m97-style ----------------
template <int MODE>
__global__ __launch_bounds__(256) void proj_gemm(const short* __restrict__ A,
                                                 const short* __restrict__ Bt,
                                                 const float* __restrict__ bias,
                                                 void* __restrict__ outp, float oscale) {
  __shared__ short As[128 * 64];
  __shared__ short Bs[128 * 64];
  const int t = threadIdx.x;
  const int w = t >> 6, l = t & 63, lr = l & 15, lg = l >> 4;
  const int rb = blockIdx.x, cb = blockIdx.y;
  const int wr = w >> 1, wc = w & 1;
  const f32x4 fz = {0.f, 0.f, 0.f, 0.f};
  f32x4 acc[4][4];
#pragma unroll
  for (int mi = 0; mi < 4; ++mi)
#pragma unroll
    for (int ni = 0; ni < 4; ++ni) acc[mi][ni] = fz;

  const int sr = l >> 3;
  const int sd = (l & 7) ^ sr;
  const short* Ag = A + ((size_t)(rb * 128 + w * 8 + sr)) * D_ + sd * 8;
  const short* Bg = Bt + ((size_t)(cb * 128 + w * 8 + sr)) * D_ + sd * 8;

  for (int k0 = 0; k0 < D_; k0 += 64) {
    __syncthreads();
#pragma unroll
    for (int i = 0; i < 4; ++i) {
      gld16(Ag + (size_t)(32 * i) * D_ + k0, &As[(4 * i + w) * 512]);
      gld16(Bg + (size_t)(32 * i) * D_ + k0, &Bs[(4 * i + w) * 512]);
    }
    __syncthreads();
#pragma unroll
    for (int kk = 0; kk < 2; ++kk) {
      bf16x8 af[4], bfr[4];
#pragma unroll
      for (int mi = 0; mi < 4; ++mi) {
        int r = wr * 64 + mi * 16 + lr;
        af[mi] = *reinterpret_cast<bf16x8*>(&As[r * 64 + (((4 * kk + lg) ^ (lr & 7)) * 8)]);
      }
#pragma unroll
      for (int ni = 0; ni < 4; ++ni) {
        int r = wc * 64 + ni * 16 + lr;
        bfr[ni] = *reinterpret_cast<bf16x8*>(&Bs[r * 64 + (((4 * kk + lg) ^ (lr & 7)) * 8)]);
      }
#pragma unroll
      for (int mi = 0; mi < 4; ++mi)
#pragma unroll
        for (int ni = 0; ni < 4; ++ni)
          acc[mi][ni] = __builtin_amdgcn_mfma_f32_16x16x32_bf16(af[mi], bfr[ni], acc[mi][ni], 0, 0, 0);
    }
  }

#pragma unroll
  for (int mi = 0; mi < 4; ++mi) {
#pragma unroll
    for (int ni = 0; ni < 4; ++ni) {
#pragma unroll
      for (int j = 0; j < 4; ++j) {
        int rr = rb * 128 + wr * 64 + mi * 16 + 4 * lg + j;
        int cc = cb * 128 + wc * 64 + ni * 16 + lr;
        float v = acc[mi][ni][j] + bias[cc];
        int b = rr >> 11, s = rr & 2047, h = cc >> 6, d = cc & 63;
        if (MODE == 0) {
          ((short*)outp)[(((size_t)(b * H_ + h)) * S_ + s) * HD_ + d] = f2bf(v * oscale);
        } else if (MODE == 1) {
          ((short*)outp)[(((size_t)(b * H_ + h)) * HD_ + d) * S_ + s] = f2bf(v);
        } else {
          ((float*)outp)[(size_t)rr * D_ + cc] = v;
        }
      }
    }
  }
}

// ---------------- fused attention: 64 q-rows/block, split-K striped, fixed-max ----------------
// Q pre-scaled by SCALE*log2(e); p = exp2(qk)/sum(exp2(qk)).
// Round-10 body with PLAIN attn stores (nontemporal removed: diagnostic r11
// showed nt caused 1.4x HBM write amplification, 1.53 GB vs 1.09 GB ideal).
__global__ __launch_bounds__(256, 2) void attn_kernel(const short* __restrict__ Q,
                                                      const short* __restrict__ K,
                                                      const short* __restrict__ Vt,
                                                      const unsigned long long* __restrict__ mT,
                                                      float* __restrict__ attn_out,
                                                      short* __restrict__ ctx) {
  __shared__ __attribute__((aligned(16))) char smem[26624];
  short* Ps  = (short*)smem;               // [4 waves][16][72] shorts (pass2 loop)
  float* mlb = (float*)(smem + 9216);      // [4][4][16] float (pass1 merge)
  float* c4  = (float*)smem;               // [4 waves][16 dcols][68] f32 (ctx merge)

  const int tid = threadIdx.x;
  const int w = tid >> 6, l = tid & 63, lr = l & 15, lg = l >> 4;
  const int bid = blockIdx.x;
  const int swz = (bid & 7) * 256 + (bid >> 3);  // bijective XCD swizzle (2048 = 8*256)
  const int qt = swz & 31, bh = swz >> 5;
  const int b = bh >> 4, h = bh & 15;

  const short* Qg = Q + ((size_t)bh * S_ + qt * 64) * HD_;
  const short* Kg = K + (size_t)bh * S_ * HD_;
  const short* Vg = Vt + (size_t)bh * HD_ * S_;
  const f32x4 fz = {0.f, 0.f, 0.f, 0.f};

  bf16x8 qf[4][2];
#pragma unroll
  for (int qa = 0; qa < 4; ++qa)
#pragma unroll
    for (int c = 0; c < 2; ++c)
      qf[qa][c] = *reinterpret_cast<const bf16x8*>(&Qg[(size_t)(16 * qa + lr) * HD_ + 32 * c + 8 * lg]);

  float ls[4] = {0.f, 0.f, 0.f, 0.f};

  // ---------- pass 1: striped sum of exp2 ----------
#pragma unroll 1
  for (int t8 = 0; t8 < 8; ++t8) {
    const int kt = t8 * 4 + w;
    const short* kb = Kg + (size_t)kt * 64 * HD_;
    bf16x8 kf[4][2];
#pragma unroll
    for (int nf = 0; nf < 4; ++nf)
#pragma unroll
      for (int c = 0; c < 2; ++c)
        kf[nf][c] = *reinterpret_cast<const bf16x8*>(&kb[(size_t)(16 * nf + lr) * HD_ + 32 * c + 8 * lg]);
    unsigned long long mw[4];
#pragma unroll
    for (int qa = 0; qa < 4; ++qa)
      mw[qa] = mT[(size_t)(b * 32 + kt) * S_ + qt * 64 + 16 * qa + lr];
    __builtin_amdgcn_sched_barrier(0);

#pragma unroll
    for (int qa = 0; qa < 4; ++qa) {
      f32x4 sc[4];
      __builtin_amdgcn_s_setprio(1);
#pragma unroll
      for (int nf = 0; nf < 4; ++nf) {
        f32x4 a = fz;
        a = __builtin_amdgcn_mfma_f32_16x16x32_bf16(kf[nf][0], qf[qa][0], a, 0, 0, 0);
        a = __builtin_amdgcn_mfma_f32_16x16x32_bf16(kf[nf][1], qf[qa][1], a, 0, 0, 0);
        sc[nf] = a;
      }
      __builtin_amdgcn_s_setprio(0);
      float acc = 0.0f;
#pragma unroll
      for (int nf = 0; nf < 4; ++nf) {
        unsigned nib = (unsigned)(mw[qa] >> (16 * nf + 4 * lg)) & 0xFu;
        float e[4];
#pragma unroll
        for (int j = 0; j < 4; ++j) {
          float v = __builtin_amdgcn_exp2f(sc[nf][j]);
          e[j] = ((nib >> j) & 1) ? 0.0f : v;
        }
        acc += (e[0] + e[1]) + (e[2] + e[3]);
      }
      ls[qa] += acc;
    }
  }
#pragma unroll
  for (int off = 16; off < 64; off <<= 1)
#pragma unroll
    for (int qa = 0; qa < 4; ++qa) ls[qa] += __shfl_xor(ls[qa], off, 64);
  if (lg == 0) {
#pragma unroll
    for (int qa = 0; qa < 4; ++qa) mlb[(w * 4 + qa) * 16 + lr] = ls[qa];
  }
  __syncthreads();
  float rl[4];
#pragma unroll
  for (int qa = 0; qa < 4; ++qa) {
    float lt = (mlb[(0 * 4 + qa) * 16 + lr] + mlb[(1 * 4 + qa) * 16 + lr]) +
               (mlb[(2 * 4 + qa) * 16 + lr] + mlb[(3 * 4 + qa) * 16 + lr]);
    rl[qa] = 1.0f / lt;
  }

  // ---------- pass 2: write normalized attn + accumulate striped ctx ----------
  f32x4 ctxa[4][4];
#pragma unroll
  for (int qa = 0; qa < 4; ++qa)
#pragma unroll
    for (int df = 0; df < 4; ++df) ctxa[qa][df] = fz;
  short* Pw = Ps + w * 16 * 72;

#pragma unroll 1
  for (int t8 = 0; t8 < 8; ++t8) {
    const int kt = t8 * 4 + w;
    const short* kb = Kg + (size_t)kt * 64 * HD_;
    bf16x8 kf[4][2], vf[4][2];
#pragma unroll
    for (int nf = 0; nf < 4; ++nf)
#pragma unroll
      for (int c = 0; c < 2; ++c)
        kf[nf][c] = *reinterpret_cast<const bf16x8*>(&kb[(size_t)(16 * nf + lr) * HD_ + 32 * c + 8 * lg]);
#pragma unroll
    for (int df = 0; df < 4; ++df)
#pragma unroll
      for (int c = 0; c < 2; ++c)
        vf[df][c] = *reinterpret_cast<const bf16x8*>(&Vg[(size_t)(16 * df + lr) * S_ + kt * 64 + 32 * c + 8 * lg]);
    unsigned long long mw[4];
#pragma unroll
    for (int qa = 0; qa < 4; ++qa)
      mw[qa] = mT[(size_t)(b * 32 + kt) * S_ + qt * 64 + 16 * qa + lr];
    __builtin_amdgcn_sched_barrier(0);

#pragma unroll
    for (int qa = 0; qa < 4; ++qa) {
      f32x4 sc[4];
      __builtin_amdgcn_s_setprio(1);
#pragma unroll
      for (int nf = 0; nf < 4; ++nf) {
        f32x4 a = fz;
        a = __builtin_amdgcn_mfma_f32_16x16x32_bf16(kf[nf][0], qf[qa][0], a, 0, 0, 0);
        a = __builtin_amdgcn_mfma_f32_16x16x32_bf16(kf[nf][1], qf[qa][1], a, 0, 0, 0);
        sc[nf] = a;
      }
      __builtin_amdgcn_s_setprio(0);
      float* arow = attn_out + ((size_t)bh * S_ + (qt * 64 + 16 * qa + lr)) * S_ + kt * 64;
      uint2 U[4];
#pragma unroll
      for (int nf = 0; nf < 4; ++nf) {
        unsigned nib = (unsigned)(mw[qa] >> (16 * nf + 4 * lg)) & 0xFu;
        f32x4 pv;
#pragma unroll
        for (int j = 0; j < 4; ++j) {
          float e = __builtin_amdgcn_exp2f(sc[nf][j]) * rl[qa];
          pv[j] = ((nib >> j) & 1) ? 0.0f : e;
        }
        *reinterpret_cast<f32x4*>(arow + 16 * nf + 4 * lg) = pv;   // plain store (no nt)
        U[nf].x = pk2(pv[0], pv[1]);
        U[nf].y = pk2(pv[2], pv[3]);
      }
#pragma unroll
      for (int nf = 0; nf < 4; ++nf)
        *reinterpret_cast<uint2*>(&Pw[lr * 72 + 16 * nf + 4 * lg]) = U[nf];
      __builtin_amdgcn_sched_barrier(0);
      asm volatile("s_waitcnt lgkmcnt(0)");
      __builtin_amdgcn_sched_barrier(0);
      bf16x8 pa0 = *reinterpret_cast<bf16x8*>(&Pw[lr * 72 + 8 * lg]);
      bf16x8 pa1 = *reinterpret_cast<bf16x8*>(&Pw[lr * 72 + 32 + 8 * lg]);
      __builtin_amdgcn_s_setprio(1);
#pragma unroll
      for (int df = 0; df < 4; ++df) {
        ctxa[qa][df] = __builtin_amdgcn_mfma_f32_16x16x32_bf16(pa0, vf[df][0], ctxa[qa][df], 0, 0, 0);
        ctxa[qa][df] = __builtin_amdgcn_mfma_f32_16x16x32_bf16(pa1, vf[df][1], ctxa[qa][df], 0, 0, 0);
      }
      __builtin_amdgcn_s_setprio(0);
    }
  }

  // ---------- cross-wave ctx reduction: 4 rounds of 16 d-columns ----------
  __syncthreads();
#pragma unroll
  for (int r = 0; r < 4; ++r) {
    if (r) __syncthreads();
#pragma unroll
    for (int qa = 0; qa < 4; ++qa)
      *reinterpret_cast<f32x4*>(&c4[(w * 16 + lr) * 68 + 16 * qa + 4 * lg]) = ctxa[qa][r];
    __syncthreads();
    int q = tid & 63, d0 = (tid >> 6) * 4;   // d0 in {0,4,8,12}
    float vs[4];
#pragma unroll
    for (int i = 0; i < 4; ++i) {
      int dl = d0 + i;
      vs[i] = (c4[(0 * 16 + dl) * 68 + q] + c4[(1 * 16 + dl) * 68 + q]) +
              (c4[(2 * 16 + dl) * 68 + q] + c4[(3 * 16 + dl) * 68 + q]);
    }
    bf16x4 o;
#pragma unroll
    for (int i = 0; i < 4; ++i) o[i] = f2bf(vs[i]);
    *reinterpret_cast<bf16x4*>(&ctx[((size_t)b * S_ + qt * 64 + q) * D_ + h * 64 + 16 * r + d0]) = o;
  }
}

extern "C" void kernel_launch(void* const* d_in, const int* in_sizes, int n_in,
                              void* d_out, int out_size, void* d_ws, size_t ws_size,
                              hipStream_t stream) {
  const float* query = (const float*)d_in[0];
  const float* key   = (const float*)d_in[1];
  const float* value = (const float*)d_in[2];
  const int*   mask  = (const int*)d_in[3];
  const float* Wq = (const float*)d_in[4];
  const float* bq = (const float*)d_in[5];
  const float* Wk = (const float*)d_in[6];
  const float* bk = (const float*)d_in[7];
  const float* Wv = (const float*)d_in[8];
  const float* bv = (const float*)d_in[9];
  const float* Wo = (const float*)d_in[10];
  const float* bo = (const float*)d_in[11];

  char* ws = (char*)d_ws;
  const size_t BIG = 16777216;  // 8192*1024*2 bytes
  short* Xbuf  = (short*)(ws);
  short* Qbuf  = (short*)(ws + BIG);
  short* Kbuf  = (short*)(ws + 2 * BIG);
  short* Vtbuf = (short*)(ws + 3 * BIG);
  short* Wqt   = (short*)(ws + 4 * BIG);
  short* Wkt   = (short*)(ws + 4 * BIG + 2097152);
  short* Wvt   = (short*)(ws + 4 * BIG + 2 * 2097152);
  short* Wot   = (short*)(ws + 4 * BIG + 3 * 2097152);
  unsigned long long* maskp = (unsigned long long*)(ws + 4 * BIG + 4 * 2097152);  // 2 MB
  short* ctx   = Xbuf;  // reuse after projections

  float* out0 = (float*)d_out;
  float* attn_out = out0 + (size_t)NB_ * S_ * D_;  // 8388608

  // pack mask to transposed bit words
  pack_mask<<<(NB_ * S_ * S_) / 256, 256, 0, stream>>>(mask, maskp);

  dim3 tcb(32, 8), tcg(32, 32);
  transpose_cast_kernel<<<tcg, tcb, 0, stream>>>(Wq, Wqt);
  transpose_cast_kernel<<<tcg, tcb, 0, stream>>>(Wk, Wkt);
  transpose_cast_kernel<<<tcg, tcb, 0, stream>>>(Wv, Wvt);
  transpose_cast_kernel<<<tcg, tcb, 0, stream>>>(Wo, Wot);

  const int n8 = (NB_ * S_ * D_) / 8;  // 1048576
  dim3 gemm_g(64, 8);
  const float QSCALE = 0.125f * 1.4426950408889634f;  // SCALE * log2(e)

  cast_kernel<<<n8 / 256, 256, 0, stream>>>(query, Xbuf, n8);
  proj_gemm<0><<<gemm_g, 256, 0, stream>>>(Xbuf, Wqt, bq, Qbuf, QSCALE);
  cast_kernel<<<n8 / 256, 256, 0, stream>>>(key, Xbuf, n8);
  proj_gemm<0><<<gemm_g, 256, 0, stream>>>(Xbuf, Wkt, bk, Kbuf, 1.0f);
  cast_kernel<<<n8 / 256, 256, 0, stream>>>(value, Xbuf, n8);
  proj_gemm<1><<<gemm_g, 256, 0, stream>>>(Xbuf, Wvt, bv, Vtbuf, 1.0f);

  attn_kernel<<<2048, 256, 0, stream>>>(Qbuf, Kbuf, Vtbuf, maskp, attn_out, ctx);

  proj_gemm<2><<<gemm_g, 256, 0, stream>>>(ctx, Wot, bo, out0, 1.0f);
}

// Round 13
// 430.063 us; speedup vs baseline: 2.5342x; 1.2605x over previous
//
#include <hip/hip_runtime.h>
#include <hip/hip_bf16.h>

#define S_    2048
#define D_    1024
#define H_    16
#define HD_   64
#define NB_   4

using bf16x8 = __attribute__((ext_vector_type(8))) short;
using bf16x4 = __attribute__((ext_vector_type(4))) short;
using f32x4  = __attribute__((ext_vector_type(4))) float;

static __device__ __forceinline__ short f2bf(float f) {
  unsigned u = __builtin_bit_cast(unsigned, f);
  u += 0x7fffu + ((u >> 16) & 1u);        // RNE
  return (short)(u >> 16);
}

// async global->LDS, 16B per lane. LDS dest is wave-uniform base + lane*16.
static __device__ __forceinline__ void gld16(const short* g, short* l) {
  __builtin_amdgcn_global_load_lds(
      (const __attribute__((address_space(1))) void*)g,
      (__attribute__((address_space(3))) void*)l, 16, 0, 0);
}

// ---------------- cast f32 -> bf16 (n multiple of 8) ----------------
__global__ __launch_bounds__(256) void cast_kernel(const float* __restrict__ src,
                                                   short* __restrict__ dst, int n8) {
  int i = blockIdx.x * 256 + threadIdx.x;
  if (i >= n8) return;
  f32x4 a = reinterpret_cast<const f32x4*>(src)[2 * i];
  f32x4 b = reinterpret_cast<const f32x4*>(src)[2 * i + 1];
  bf16x8 o;
  o[0] = f2bf(a[0]); o[1] = f2bf(a[1]); o[2] = f2bf(a[2]); o[3] = f2bf(a[3]);
  o[4] = f2bf(b[0]); o[5] = f2bf(b[1]); o[6] = f2bf(b[2]); o[7] = f2bf(b[3]);
  reinterpret_cast<bf16x8*>(dst)[i] = o;
}

// ---------------- pack mask int32 -> TRANSPOSED bitmask ----------------
__global__ __launch_bounds__(256) void pack_mask(const int* __restrict__ mask,
                                                 unsigned long long* __restrict__ mp) {
  int i = blockIdx.x * 256 + threadIdx.x;   // i = (b*S + q)*S + k
  unsigned long long bits = __ballot(mask[i] != 0);
  if ((threadIdx.x & 63) == 0) {
    int k = i & 2047;
    int q = (i >> 11) & 2047;
    int b = i >> 22;
    mp[((size_t)(b * 32 + (k >> 6))) * 2048 + q] = bits;
  }
}

// ---------------- Wt[n][k] = (bf16) W[k][n], 1024x1024 ----------------
__global__ __launch_bounds__(256) void transpose_cast_kernel(const float* __restrict__ W,
                                                             short* __restrict__ Wt) {
  __shared__ float tile[32][33];
  int tx = threadIdx.x, ty = threadIdx.y;           // (32, 8)
  int bx = blockIdx.x * 32, by = blockIdx.y * 32;
#pragma unroll
  for (int i = 0; i < 4; ++i) {
    int k = ty + 8 * i;
    tile[k][tx] = W[(size_t)(by + k) * D_ + bx + tx];
  }
  __syncthreads();
#pragma unroll
  for (int i = 0; i < 4; ++i) {
    int n = ty + 8 * i;
    Wt[(size_t)(bx + n) * D_ + by + tx] = f2bf(tile[tx][n]);
  }
}

// ---------------- GEMM: out = A[8192x1024] @ Bt^T + bias, m97-style ----------------
template <int MODE>
__global__ __launch_bounds__(256) void proj_gemm(const short* __restrict__ A,
                                                 const short* __restrict__ Bt,
                                                 const float* __restrict__ bias,
                                                 void* __restrict__ outp, float oscale) {
  __shared__ short As[128 * 64];
  __shared__ short Bs[128 * 64];
  const int t = threadIdx.x;
  const int w = t >> 6, l = t & 63, lr = l & 15, lg = l >> 4;
  const int rb = blockIdx.x, cb = blockIdx.y;
  const int wr = w >> 1, wc = w & 1;
  const f32x4 fz = {0.f, 0.f, 0.f, 0.f};
  f32x4 acc[4][4];
#pragma unroll
  for (int mi = 0; mi < 4; ++mi)
#pragma unroll
    for (int ni = 0; ni < 4; ++ni) acc[mi][ni] = fz;

  const int sr = l >> 3;
  const int sd = (l & 7) ^ sr;
  const short* Ag = A + ((size_t)(rb * 128 + w * 8 + sr)) * D_ + sd * 8;
  const short* Bg = Bt + ((size_t)(cb * 128 + w * 8 + sr)) * D_ + sd * 8;

  for (int k0 = 0; k0 < D_; k0 += 64) {
    __syncthreads();
#pragma unroll
    for (int i = 0; i < 4; ++i) {
      gld16(Ag + (size_t)(32 * i) * D_ + k0, &As[(4 * i + w) * 512]);
      gld16(Bg + (size_t)(32 * i) * D_ + k0, &Bs[(4 * i + w) * 512]);
    }
    __syncthreads();
#pragma unroll
    for (int kk = 0; kk < 2; ++kk) {
      bf16x8 af[4], bfr[4];
#pragma unroll
      for (int mi = 0; mi < 4; ++mi) {
        int r = wr * 64 + mi * 16 + lr;
        af[mi] = *reinterpret_cast<bf16x8*>(&As[r * 64 + (((4 * kk + lg) ^ (lr & 7)) * 8)]);
      }
#pragma unroll
      for (int ni = 0; ni < 4; ++ni) {
        int r = wc * 64 + ni * 16 + lr;
        bfr[ni] = *reinterpret_cast<bf16x8*>(&Bs[r * 64 + (((4 * kk + lg) ^ (lr & 7)) * 8)]);
      }
#pragma unroll
      for (int mi = 0; mi < 4; ++mi)
#pragma unroll
        for (int ni = 0; ni < 4; ++ni)
          acc[mi][ni] = __builtin_amdgcn_mfma_f32_16x16x32_bf16(af[mi], bfr[ni], acc[mi][ni], 0, 0, 0);
    }
  }

#pragma unroll
  for (int mi = 0; mi < 4; ++mi) {
#pragma unroll
    for (int ni = 0; ni < 4; ++ni) {
#pragma unroll
      for (int j = 0; j < 4; ++j) {
        int rr = rb * 128 + wr * 64 + mi * 16 + 4 * lg + j;
        int cc = cb * 128 + wc * 64 + ni * 16 + lr;
        float v = acc[mi][ni][j] + bias[cc];
        int b = rr >> 11, s = rr & 2047, h = cc >> 6, d = cc & 63;
        if (MODE == 0) {
          ((short*)outp)[(((size_t)(b * H_ + h)) * S_ + s) * HD_ + d] = f2bf(v * oscale);
        } else if (MODE == 1) {
          ((short*)outp)[(((size_t)(b * H_ + h)) * HD_ + d) * S_ + s] = f2bf(v);
        } else {
          ((float*)outp)[(size_t)rr * D_ + cc] = v;
        }
      }
    }
  }
}

// ---------------- fused attention: 64 q-rows/block, split-K striped, fixed-max ----------------
// Q pre-scaled by SCALE*log2(e); p = exp2(qk)/sum(exp2(qk)).
// r10 body; pass-2 store path re-coalesced: pv goes to f32 LDS tile, then
// (a) bf16 PV fragments read back, (b) nt stores issued as 4-row x 256B
// row-contiguous spans so every 128B line is covered by ONE instruction
// (fixes r11's 1.4x nt write amplification).
__global__ __launch_bounds__(256, 2) void attn_kernel(const short* __restrict__ Q,
                                                      const short* __restrict__ K,
                                                      const short* __restrict__ Vt,
                                                      const unsigned long long* __restrict__ mT,
                                                      float* __restrict__ attn_out,
                                                      short* __restrict__ ctx) {
  // 26624 B declared => 6 blocks/CU residency (L2-safe working set).
  __shared__ __attribute__((aligned(16))) char smem[26624];
  float* Pf  = (float*)smem;               // [4 waves][16 q][68] f32 P tile = 17408 B
  float* mlb = (float*)(smem + 17408);     // [4][4][16] float (pass1 merge) = 1024 B
  float* c4  = (float*)smem;               // [4 waves][16 dcols][68] f32 (ctx merge, reuses Pf)

  const int tid = threadIdx.x;
  const int w = tid >> 6, l = tid & 63, lr = l & 15, lg = l >> 4;
  const int bid = blockIdx.x;
  const int swz = (bid & 7) * 256 + (bid >> 3);  // bijective XCD swizzle (2048 = 8*256)
  const int qt = swz & 31, bh = swz >> 5;
  const int b = bh >> 4, h = bh & 15;

  const short* Qg = Q + ((size_t)bh * S_ + qt * 64) * HD_;
  const short* Kg = K + (size_t)bh * S_ * HD_;
  const short* Vg = Vt + (size_t)bh * HD_ * S_;
  const f32x4 fz = {0.f, 0.f, 0.f, 0.f};

  bf16x8 qf[4][2];
#pragma unroll
  for (int qa = 0; qa < 4; ++qa)
#pragma unroll
    for (int c = 0; c < 2; ++c)
      qf[qa][c] = *reinterpret_cast<const bf16x8*>(&Qg[(size_t)(16 * qa + lr) * HD_ + 32 * c + 8 * lg]);

  float ls[4] = {0.f, 0.f, 0.f, 0.f};

  // ---------- pass 1: striped sum of exp2 ----------
#pragma unroll 1
  for (int t8 = 0; t8 < 8; ++t8) {
    const int kt = t8 * 4 + w;
    const short* kb = Kg + (size_t)kt * 64 * HD_;
    bf16x8 kf[4][2];
#pragma unroll
    for (int nf = 0; nf < 4; ++nf)
#pragma unroll
      for (int c = 0; c < 2; ++c)
        kf[nf][c] = *reinterpret_cast<const bf16x8*>(&kb[(size_t)(16 * nf + lr) * HD_ + 32 * c + 8 * lg]);
    unsigned long long mw[4];
#pragma unroll
    for (int qa = 0; qa < 4; ++qa)
      mw[qa] = mT[(size_t)(b * 32 + kt) * S_ + qt * 64 + 16 * qa + lr];
    __builtin_amdgcn_sched_barrier(0);

#pragma unroll
    for (int qa = 0; qa < 4; ++qa) {
      f32x4 sc[4];
      __builtin_amdgcn_s_setprio(1);
#pragma unroll
      for (int nf = 0; nf < 4; ++nf) {
        f32x4 a = fz;
        a = __builtin_amdgcn_mfma_f32_16x16x32_bf16(kf[nf][0], qf[qa][0], a, 0, 0, 0);
        a = __builtin_amdgcn_mfma_f32_16x16x32_bf16(kf[nf][1], qf[qa][1], a, 0, 0, 0);
        sc[nf] = a;
      }
      __builtin_amdgcn_s_setprio(0);
      float acc = 0.0f;
#pragma unroll
      for (int nf = 0; nf < 4; ++nf) {
        unsigned nib = (unsigned)(mw[qa] >> (16 * nf + 4 * lg)) & 0xFu;
        float e[4];
#pragma unroll
        for (int j = 0; j < 4; ++j) {
          float v = __builtin_amdgcn_exp2f(sc[nf][j]);
          e[j] = ((nib >> j) & 1) ? 0.0f : v;
        }
        acc += (e[0] + e[1]) + (e[2] + e[3]);
      }
      ls[qa] += acc;
    }
  }
#pragma unroll
  for (int off = 16; off < 64; off <<= 1)
#pragma unroll
    for (int qa = 0; qa < 4; ++qa) ls[qa] += __shfl_xor(ls[qa], off, 64);
  if (lg == 0) {
#pragma unroll
    for (int qa = 0; qa < 4; ++qa) mlb[(w * 4 + qa) * 16 + lr] = ls[qa];
  }
  __syncthreads();
  float rl[4];
#pragma unroll
  for (int qa = 0; qa < 4; ++qa) {
    float lt = (mlb[(0 * 4 + qa) * 16 + lr] + mlb[(1 * 4 + qa) * 16 + lr]) +
               (mlb[(2 * 4 + qa) * 16 + lr] + mlb[(3 * 4 + qa) * 16 + lr]);
    rl[qa] = 1.0f / lt;
  }

  // ---------- pass 2: coalesced attn write + striped ctx ----------
  f32x4 ctxa[4][4];
#pragma unroll
  for (int qa = 0; qa < 4; ++qa)
#pragma unroll
    for (int df = 0; df < 4; ++df) ctxa[qa][df] = fz;
  float* Pw = Pf + w * 16 * 68;            // this wave's [16 q][68] f32 tile
  const int srow = l >> 4;                 // 0..3 (store pass row-group)
  const int scol = (l & 15) * 4;           // 0..60 (store pass col, floats)

#pragma unroll 1
  for (int t8 = 0; t8 < 8; ++t8) {
    const int kt = t8 * 4 + w;
    const short* kb = Kg + (size_t)kt * 64 * HD_;
    bf16x8 kf[4][2], vf[4][2];
#pragma unroll
    for (int nf = 0; nf < 4; ++nf)
#pragma unroll
      for (int c = 0; c < 2; ++c)
        kf[nf][c] = *reinterpret_cast<const bf16x8*>(&kb[(size_t)(16 * nf + lr) * HD_ + 32 * c + 8 * lg]);
#pragma unroll
    for (int df = 0; df < 4; ++df)
#pragma unroll
      for (int c = 0; c < 2; ++c)
        vf[df][c] = *reinterpret_cast<const bf16x8*>(&Vg[(size_t)(16 * df + lr) * S_ + kt * 64 + 32 * c + 8 * lg]);
    unsigned long long mw[4];
#pragma unroll
    for (int qa = 0; qa < 4; ++qa)
      mw[qa] = mT[(size_t)(b * 32 + kt) * S_ + qt * 64 + 16 * qa + lr];
    __builtin_amdgcn_sched_barrier(0);

#pragma unroll
    for (int qa = 0; qa < 4; ++qa) {
      f32x4 sc[4];
      __builtin_amdgcn_s_setprio(1);
#pragma unroll
      for (int nf = 0; nf < 4; ++nf) {
        f32x4 a = fz;
        a = __builtin_amdgcn_mfma_f32_16x16x32_bf16(kf[nf][0], qf[qa][0], a, 0, 0, 0);
        a = __builtin_amdgcn_mfma_f32_16x16x32_bf16(kf[nf][1], qf[qa][1], a, 0, 0, 0);
        sc[nf] = a;
      }
      __builtin_amdgcn_s_setprio(0);
      // P values -> f32 LDS tile (q-row lr, cols 16nf+4lg..+3)
#pragma unroll
      for (int nf = 0; nf < 4; ++nf) {
        unsigned nib = (unsigned)(mw[qa] >> (16 * nf + 4 * lg)) & 0xFu;
        f32x4 pv;
#pragma unroll
        for (int j = 0; j < 4; ++j) {
          float e = __builtin_amdgcn_exp2f(sc[nf][j]) * rl[qa];
          pv[j] = ((nib >> j) & 1) ? 0.0f : e;
        }
        *reinterpret_cast<f32x4*>(&Pw[lr * 68 + 16 * nf + 4 * lg]) = pv;
      }
      __builtin_amdgcn_sched_barrier(0);
      asm volatile("s_waitcnt lgkmcnt(0)");
      __builtin_amdgcn_sched_barrier(0);
      // (a) PV fragments: P[q=lr][32c+8lg+j] as bf16
      f32x4 f0 = *reinterpret_cast<f32x4*>(&Pw[lr * 68 + 8 * lg]);
      f32x4 f1 = *reinterpret_cast<f32x4*>(&Pw[lr * 68 + 8 * lg + 4]);
      f32x4 f2 = *reinterpret_cast<f32x4*>(&Pw[lr * 68 + 32 + 8 * lg]);
      f32x4 f3 = *reinterpret_cast<f32x4*>(&Pw[lr * 68 + 32 + 8 * lg + 4]);
      bf16x8 pa0, pa1;
#pragma unroll
      for (int i = 0; i < 4; ++i) {
        pa0[i] = f2bf(f0[i]); pa0[4 + i] = f2bf(f1[i]);
        pa1[i] = f2bf(f2[i]); pa1[4 + i] = f2bf(f3[i]);
      }
      __builtin_amdgcn_s_setprio(1);
#pragma unroll
      for (int df = 0; df < 4; ++df) {
        ctxa[qa][df] = __builtin_amdgcn_mfma_f32_16x16x32_bf16(pa0, vf[df][0], ctxa[qa][df], 0, 0, 0);
        ctxa[qa][df] = __builtin_amdgcn_mfma_f32_16x16x32_bf16(pa1, vf[df][1], ctxa[qa][df], 0, 0, 0);
      }
      __builtin_amdgcn_s_setprio(0);
      // (b) coalesced nt store: 4 instrs x (4 rows x 256B), full 128B lines
      float* abase = attn_out + ((size_t)bh * S_ + qt * 64 + 16 * qa) * S_ + kt * 64;
#pragma unroll
      for (int p = 0; p < 4; ++p) {
        int r16 = p * 4 + srow;
        f32x4 d = *reinterpret_cast<f32x4*>(&Pw[r16 * 68 + scol]);
        __builtin_nontemporal_store(d, (f32x4*)(abase + (size_t)r16 * S_ + scol));
      }
    }
  }

  // ---------- cross-wave ctx reduction: 4 rounds of 16 d-columns ----------
  __syncthreads();
#pragma unroll
  for (int r = 0; r < 4; ++r) {
    if (r) __syncthreads();
#pragma unroll
    for (int qa = 0; qa < 4; ++qa)
      *reinterpret_cast<f32x4*>(&c4[(w * 16 + lr) * 68 + 16 * qa + 4 * lg]) = ctxa[qa][r];
    __syncthreads();
    int q = tid & 63, d0 = (tid >> 6) * 4;   // d0 in {0,4,8,12}
    float vs[4];
#pragma unroll
    for (int i = 0; i < 4; ++i) {
      int dl = d0 + i;
      vs[i] = (c4[(0 * 16 + dl) * 68 + q] + c4[(1 * 16 + dl) * 68 + q]) +
              (c4[(2 * 16 + dl) * 68 + q] + c4[(3 * 16 + dl) * 68 + q]);
    }
    bf16x4 o;
#pragma unroll
    for (int i = 0; i < 4; ++i) o[i] = f2bf(vs[i]);
    *reinterpret_cast<bf16x4*>(&ctx[((size_t)b * S_ + qt * 64 + q) * D_ + h * 64 + 16 * r + d0]) = o;
  }
}

extern "C" void kernel_launch(void* const* d_in, const int* in_sizes, int n_in,
                              void* d_out, int out_size, void* d_ws, size_t ws_size,
                              hipStream_t stream) {
  const float* query = (const float*)d_in[0];
  const float* key   = (const float*)d_in[1];
  const float* value = (const float*)d_in[2];
  const int*   mask  = (const int*)d_in[3];
  const float* Wq = (const float*)d_in[4];
  const float* bq = (const float*)d_in[5];
  const float* Wk = (const float*)d_in[6];
  const float* bk = (const float*)d_in[7];
  const float* Wv = (const float*)d_in[8];
  const float* bv = (const float*)d_in[9];
  const float* Wo = (const float*)d_in[10];
  const float* bo = (const float*)d_in[11];

  char* ws = (char*)d_ws;
  const size_t BIG = 16777216;  // 8192*1024*2 bytes
  short* Xbuf  = (short*)(ws);
  short* Qbuf  = (short*)(ws + BIG);
  short* Kbuf  = (short*)(ws + 2 * BIG);
  short* Vtbuf = (short*)(ws + 3 * BIG);
  short* Wqt   = (short*)(ws + 4 * BIG);
  short* Wkt   = (short*)(ws + 4 * BIG + 2097152);
  short* Wvt   = (short*)(ws + 4 * BIG + 2 * 2097152);
  short* Wot   = (short*)(ws + 4 * BIG + 3 * 2097152);
  unsigned long long* maskp = (unsigned long long*)(ws + 4 * BIG + 4 * 2097152);  // 2 MB
  short* ctx   = Xbuf;  // reuse after projections

  float* out0 = (float*)d_out;
  float* attn_out = out0 + (size_t)NB_ * S_ * D_;  // 8388608

  // pack mask to transposed bit words
  pack_mask<<<(NB_ * S_ * S_) / 256, 256, 0, stream>>>(mask, maskp);

  dim3 tcb(32, 8), tcg(32, 32);
  transpose_cast_kernel<<<tcg, tcb, 0, stream>>>(Wq, Wqt);
  transpose_cast_kernel<<<tcg, tcb, 0, stream>>>(Wk, Wkt);
  transpose_cast_kernel<<<tcg, tcb, 0, stream>>>(Wv, Wvt);
  transpose_cast_kernel<<<tcg, tcb, 0, stream>>>(Wo, Wot);

  const int n8 = (NB_ * S_ * D_) / 8;  // 1048576
  dim3 gemm_g(64, 8);
  const float QSCALE = 0.125f * 1.4426950408889634f;  // SCALE * log2(e)

  cast_kernel<<<n8 / 256, 256, 0, stream>>>(query, Xbuf, n8);
  proj_gemm<0><<<gemm_g, 256, 0, stream>>>(Xbuf, Wqt, bq, Qbuf, QSCALE);
  cast_kernel<<<n8 / 256, 256, 0, stream>>>(key, Xbuf, n8);
  proj_gemm<0><<<gemm_g, 256, 0, stream>>>(Xbuf, Wkt, bk, Kbuf, 1.0f);
  cast_kernel<<<n8 / 256, 256, 0, stream>>>(value, Xbuf, n8);
  proj_gemm<1><<<gemm_g, 256, 0, stream>>>(Xbuf, Wvt, bv, Vtbuf, 1.0f);

  attn_kernel<<<2048, 256, 0, stream>>>(Qbuf, Kbuf, Vtbuf, maskp, attn_out, ctx);

  proj_gemm<2><<<gemm_g, 256, 0, stream>>>(ctx, Wot, bo, out0, 1.0f);
}